// Round 17
// baseline (1697.424 us; speedup 1.0000x reference)
//
#include <hip/hip_runtime.h>

#define T_  512
#define B_  128
#define D_  512
#define H_  512
#define N4H 2048

typedef _Float16 half8  __attribute__((ext_vector_type(8)));
typedef _Float16 half4v __attribute__((ext_vector_type(4)));
typedef float    f32x4  __attribute__((ext_vector_type(4)));

#if __has_builtin(__builtin_amdgcn_global_load_lds)
#define ASYNC_B 1
#endif

// ---------- fused weight converts ----------
__global__ void cvt_weights(const float* __restrict__ Wi, const float* __restrict__ Wh,
                            _Float16* __restrict__ WiT, _Float16* __restrict__ WhgT) {
    const int bid = blockIdx.x;
    if (bid < 4096) {                                  // WiT[n][k] = Wi[k][n]
        int i = bid * 256 + threadIdx.x;
        int k = i >> 11, n = i & 2047;
        WiT[n * D_ + k] = (_Float16)Wi[i];
    } else {                                           // lane-linear WhgT
        int i = (bid - 4096) * 256 + threadIdx.x;
        int k = i >> 11, c = i & 2047;
        int g = c >> 9, j = c & 511;
        int cp16 = (j >> 4) * 4 + g;
        int jlo = j & 15;
        int ks = k >> 5, kg = (k >> 3) & 3, e = k & 7;
        WhgT[(size_t)cp16 * 8192 + ks * 512 + (kg * 16 + jlo) * 8 + e] = (_Float16)Wh[i];
    }
}

// ---------- phase 1: Zg = ins @ WiT^T + bias, layout [it][j][g], coalesced writes ----------
__global__ __launch_bounds__(256) void gemm_xwi(const float* __restrict__ X,
                                                const _Float16* __restrict__ WT,
                                                const float* __restrict__ bv,
                                                _Float16* __restrict__ Zg) {
    __shared__ __attribute__((aligned(16))) _Float16 As[128 * 32];
    __shared__ __attribute__((aligned(16))) _Float16 Bs[128 * 32];
    __shared__ __attribute__((aligned(16))) _Float16 Cs[128 * 128];   // 32KB transpose buf
    const int tid  = threadIdx.x;
    const int lane = tid & 63;
    const int wid  = tid >> 6;
    const int wm   = wid >> 1, wn = wid & 1;
    const int bm   = blockIdx.x, bn = blockIdx.y;

    f32x4 acc[4][4];
    for (int m = 0; m < 4; ++m)
        for (int n = 0; n < 4; ++n)
            acc[m][n] = (f32x4){0.f, 0.f, 0.f, 0.f};

    const float* Xb = X + (size_t)bm * 128 * D_;

    for (int kt = 0; kt < D_ / 32; ++kt) {
        if (kt) __syncthreads();
        #pragma unroll
        for (int s = 0; s < 2; ++s) {
            int idx = tid + s * 256;
            int row = idx >> 2, cg = idx & 3;          // row = tile-col tc for B
            const int wcol = (row >> 5) * 512 + bn * 32 + (row & 31);
#ifdef ASYNC_B
            __builtin_amdgcn_global_load_lds(
                (const __attribute__((address_space(1))) void*)(WT + (size_t)wcol * D_ + kt * 32 + cg * 8),
                (__attribute__((address_space(3))) void*)&Bs[idx * 8], 16, 0, 0);
#else
            *(half8*)&Bs[idx * 8] = *(const half8*)&WT[(size_t)wcol * D_ + kt * 32 + cg * 8];
#endif
            const float* ap = Xb + (size_t)row * D_ + kt * 32 + cg * 8;
            float4 f0 = *(const float4*)ap, f1 = *(const float4*)(ap + 4);
            half8 hv;
            hv[0]=(_Float16)f0.x; hv[1]=(_Float16)f0.y; hv[2]=(_Float16)f0.z; hv[3]=(_Float16)f0.w;
            hv[4]=(_Float16)f1.x; hv[5]=(_Float16)f1.y; hv[6]=(_Float16)f1.z; hv[7]=(_Float16)f1.w;
            *(half8*)&As[idx * 8] = hv;
        }
        __syncthreads();
        half8 a[4], b[4];
        #pragma unroll
        for (int m = 0; m < 4; ++m)
            a[m] = *(const half8*)&As[(wm * 64 + m * 16 + (lane & 15)) * 32 + (lane >> 4) * 8];
        #pragma unroll
        for (int n = 0; n < 4; ++n)
            b[n] = *(const half8*)&Bs[(wn * 64 + n * 16 + (lane & 15)) * 32 + (lane >> 4) * 8];
        #pragma unroll
        for (int m = 0; m < 4; ++m)
            #pragma unroll
            for (int n = 0; n < 4; ++n)
                acc[m][n] = __builtin_amdgcn_mfma_f32_16x16x32_f16(a[m], b[n], acc[m][n], 0, 0, 0);
    }

    // epilogue: acc -> Cs (transpose to [r][jj*4+g]) -> coalesced Zg
    const int jlo = lane & 15, kg = lane >> 4;
    float biasv[4];
    #pragma unroll
    for (int n = 0; n < 4; ++n) {
        const int tc = wn * 64 + n * 16 + jlo;
        biasv[n] = bv[(tc >> 5) * 512 + bn * 32 + (tc & 31)];
    }
    #pragma unroll
    for (int m = 0; m < 4; ++m)
        #pragma unroll
        for (int n = 0; n < 4; ++n) {
            const int tc = wn * 64 + n * 16 + jlo;
            const int cj = (tc & 31) * 4 + (tc >> 5);  // jj*4+g
            #pragma unroll
            for (int e = 0; e < 4; ++e) {
                const int rl = wm * 64 + m * 16 + kg * 4 + e;
                Cs[rl * 128 + cj] = (_Float16)(acc[m][n][e] + biasv[n]);
            }
        }
    __syncthreads();
    #pragma unroll
    for (int p = 0; p < 8; ++p) {
        const int row = p * 16 + (tid >> 4);
        const int u   = tid & 15;
        *(half8*)&Zg[(size_t)(bm * 128 + row) * N4H + bn * 128 + u * 8] =
            *(const half8*)&Cs[row * 128 + u * 8];
    }
}

// ---------- chain analysis: build length-sorted chain list ----------
// word: [len:10 @17][b:7 @10][t_start:9 @1][useInit:1 @0]
__global__ void chain_analysis(const int* __restrict__ resets,
                               int* __restrict__ chainU,     // [128*512] scratch
                               int* __restrict__ chains,     // sorted desc by len
                               int* __restrict__ meta) {     // [0]=nch [1]=ntiles
    __shared__ int cnt[513];
    __shared__ int cur[513];
    const int tid = threadIdx.x;
    for (int i = tid; i < 513; i += 256) cnt[i] = 0;
    __syncthreads();
    int nc = 0;
    if (tid < 128) {
        const int b = tid;
        int start = 0;
        int ini = (resets[b] == 0);        // t=0 chain uses h0/c0 iff no reset at t=0
        for (int t = 1; t <= T_; ++t) {
            bool cut = (t == T_) || (resets[t * B_ + b] != 0);
            if (cut) {
                int len = t - start;
                chainU[b * 512 + nc] = (len << 17) | (b << 10) | (start << 1) | ini;
                ++nc;
                atomicAdd(&cnt[len], 1);
                start = t; ini = 0;
            }
        }
    }
    __syncthreads();
    if (tid == 0) {
        int off = 0;
        for (int l = 512; l >= 1; --l) { cur[l] = off; off += cnt[l]; }
        meta[0] = off;
        meta[1] = (off + 31) >> 5;
    }
    __syncthreads();
    if (tid < 128) {
        const int b = tid;
        for (int k = 0; k < nc; ++k) {
            int w = chainU[b * 512 + k];
            int pos = atomicAdd(&cur[w >> 17], 1);
            chains[pos] = w;
        }
    }
}

// ---------- phase 2: chain-parallel scan. One block per 32-chain tile. ----------
// No inter-block sync. h in double-buffered LDS (MFMA layout); c in registers.
__global__ __launch_bounds__(512) void lstm_chain(const _Float16* __restrict__ Zg,
                                                  const _Float16* __restrict__ WhgT,
                                                  const float* __restrict__ c0,
                                                  const float* __restrict__ h0,
                                                  const int* __restrict__ chains,
                                                  const int* __restrict__ meta,
                                                  float* __restrict__ out) {
    const int ntiles = meta[1];
    const int tile = blockIdx.x;
    if (tile >= ntiles) return;
    const int nch = meta[0];
    const int tid  = threadIdx.x;
    const int lane = tid & 63;
    const int wg   = tid >> 8;                 // wavegroup 0/1 -> ct pair
    const int lw   = (tid & 255) >> 6;         // wave in group
    const int jlo  = lane & 15, kg = lane >> 4;
    float* ys = out + 2 * (B_ * H_);

    __shared__ int cwS[32];
    __shared__ int needW;
    __shared__ _Float16 A[2][32 * 512];        // 2 x 32KB h-state, chunk-XOR swizzled

    if (tid == 0) needW = 0;
    __syncthreads();
    if (tid < 32) {
        int idx = tile * 32 + tid;
        int w = (idx < nch) ? chains[idx] : 0;
        cwS[tid] = w;
        if ((w >> 17) > 1 || (w & 1)) atomicOr(&needW, 1);
    }
    __syncthreads();
    const int maxlen = cwS[0] >> 17;           // sorted desc
    const bool useW = (needW != 0);

    int cw_[2][4];
    #pragma unroll
    for (int m = 0; m < 2; ++m)
        #pragma unroll
        for (int e = 0; e < 4; ++e)
            cw_[m][e] = cwS[m * 16 + kg * 4 + e];

    float c_reg[2][2][2][4];                   // [ct2][jh][m][e]
    #pragma unroll
    for (int c2 = 0; c2 < 2; ++c2) {
        const int ct = wg * 2 + c2;
        #pragma unroll
        for (int jh = 0; jh < 2; ++jh) {
            const int j = (ct * 8 + lw * 2 + jh) * 16 + jlo;
            #pragma unroll
            for (int m = 0; m < 2; ++m)
                #pragma unroll
                for (int e = 0; e < 4; ++e) {
                    const int rr = m * 16 + kg * 4 + e;
                    const int w = cw_[m][e];
                    float hi = 0.f, ci = 0.f;
                    if (w & 1) {               // t0-chain with live h0/c0
                        const int b = (w >> 10) & 127;
                        hi = h0[b * 512 + j];
                        ci = c0[b * 512 + j];
                    }
                    c_reg[c2][jh][m][e] = ci;
                    A[0][(rr * 64 + ((j >> 3) ^ (rr & 7))) * 8 + (j & 7)] = (_Float16)hi;
                }
        }
    }
    __syncthreads();

    for (int s = 0; s < maxlen; ++s) {
        const int cu = s & 1;
        #pragma unroll
        for (int c2 = 0; c2 < 2; ++c2) {
            const int ct = wg * 2 + c2;
            #pragma unroll
            for (int jh = 0; jh < 2; ++jh) {
                const int j = (ct * 8 + lw * 2 + jh) * 16 + jlo;

                // prefetch Zg gates + (acc under MFMA)
                half4v g4p[2][4];
                #pragma unroll
                for (int m = 0; m < 2; ++m)
                    #pragma unroll
                    for (int e = 0; e < 4; ++e) {
                        const int w = cw_[m][e];
                        if (s < (w >> 17)) {
                            const int b = (w >> 10) & 127;
                            const int t = ((w >> 1) & 511) + s;
                            g4p[m][e] = *(const half4v*)&Zg[(size_t)(t * B_ + b) * N4H + j * 4];
                        }
                    }

                f32x4 acc[2][4];
                #pragma unroll
                for (int m = 0; m < 2; ++m)
                    #pragma unroll
                    for (int f = 0; f < 4; ++f) acc[m][f] = (f32x4){0.f, 0.f, 0.f, 0.f};

                if (useW) {
                    #pragma unroll 2
                    for (int ks = 0; ks < 16; ++ks) {
                        half8 av[2];
                        #pragma unroll
                        for (int m = 0; m < 2; ++m) {
                            const int row = m * 16 + jlo;
                            av[m] = *(const half8*)&A[cu][(row * 64 + ((ks * 4 + kg) ^ (row & 7))) * 8];
                        }
                        #pragma unroll
                        for (int fc = 0; fc < 4; ++fc) {
                            const half8 bv8 = *(const half8*)&WhgT[(size_t)(ct * 32 + lw * 8 + jh * 4 + fc) * 8192 + ks * 512 + lane * 8];
                            #pragma unroll
                            for (int m = 0; m < 2; ++m)
                                acc[m][fc] = __builtin_amdgcn_mfma_f32_16x16x32_f16(av[m], bv8, acc[m][fc], 0, 0, 0);
                        }
                    }
                }

                // epilogue: gates, c update (registers), h -> A[next]
                #pragma unroll
                for (int m = 0; m < 2; ++m)
                    #pragma unroll
                    for (int e = 0; e < 4; ++e) {
                        const int w = cw_[m][e];
                        if (s < (w >> 17)) {
                            const int rr = m * 16 + kg * 4 + e;
                            const int b = (w >> 10) & 127;
                            const int t = ((w >> 1) & 511) + s;
                            float zv[4];
                            #pragma unroll
                            for (int g = 0; g < 4; ++g)
                                zv[g] = acc[m][g][e] + (float)g4p[m][e][g];
                            const float ci = c_reg[c2][jh][m][e];
                            float ig = 1.f / (1.f + __expf(-zv[0]));
                            float fg = 1.f / (1.f + __expf(-zv[1]));
                            float gg = 1.f - 2.f / (1.f + __expf(2.f * zv[2]));
                            float og = 1.f / (1.f + __expf(-zv[3]));
                            float cn = fg * ci + ig * gg;
                            float hn = og * (1.f - 2.f / (1.f + __expf(2.f * cn)));
                            c_reg[c2][jh][m][e] = cn;
                            A[cu ^ 1][(rr * 64 + ((j >> 3) ^ (rr & 7))) * 8 + (j & 7)] = (_Float16)hn;
                            float cn1 = __shfl_down(cn, 1);
                            float hn1 = __shfl_down(hn, 1);
                            if (!(jlo & 1)) {
                                *(float2*)&ys[(size_t)(t * B_ + b) * 512 + j] = (float2){hn, hn1};
                                if (t == T_ - 1) {
                                    *(float2*)&out[b * 512 + j]            = (float2){cn, cn1};
                                    *(float2*)&out[B_ * H_ + b * 512 + j]  = (float2){hn, hn1};
                                }
                            }
                        }
                    }
            }
        }
        __syncthreads();                        // A[next] complete for step s+1
    }
}

// ---------- fallback: all-f32 fused ----------
__global__ __launch_bounds__(512) void lstm_fb(const float* __restrict__ ins,
                                               const int* __restrict__ resets,
                                               const float* __restrict__ c0,
                                               const float* __restrict__ h0,
                                               const float* __restrict__ Wi,
                                               const float* __restrict__ Wh,
                                               const float* __restrict__ bv,
                                               float* __restrict__ out) {
    const int b = blockIdx.x;
    const int j = threadIdx.x;
    __shared__ float hs[H_];
    __shared__ float xs[D_];
    float c = c0[b * H_ + j];
    hs[j] = h0[b * H_ + j];
    const float b0 = bv[j], b1 = bv[H_ + j], b2 = bv[2 * H_ + j], b3 = bv[3 * H_ + j];
    float* ys = out + 2 * B_ * H_;
    for (int t = 0; t < T_; ++t) {
        __syncthreads();
        xs[j] = ins[((size_t)(t * B_ + b)) * D_ + j];
        __syncthreads();
        const bool rst = resets[t * B_ + b] != 0;
        float z0 = b0, z1 = b1, z2 = b2, z3 = b3;
        for (int k = 0; k < D_; ++k) {
            float xk = xs[k];
            z0 += xk * Wi[(size_t)k * N4H + j];
            z1 += xk * Wi[(size_t)k * N4H + H_ + j];
            z2 += xk * Wi[(size_t)k * N4H + 2 * H_ + j];
            z3 += xk * Wi[(size_t)k * N4H + 3 * H_ + j];
        }
        float c_use = rst ? 0.f : c;
        if (!rst) {
            for (int k = 0; k < H_; ++k) {
                float hk = hs[k];
                z0 += hk * Wh[(size_t)k * N4H + j];
                z1 += hk * Wh[(size_t)k * N4H + H_ + j];
                z2 += hk * Wh[(size_t)k * N4H + 2 * H_ + j];
                z3 += hk * Wh[(size_t)k * N4H + 3 * H_ + j];
            }
        }
        float ig = 1.f / (1.f + __expf(-z0));
        float fg = 1.f / (1.f + __expf(-z1));
        float gg = 1.f - 2.f / (1.f + __expf(2.f * z2));
        float og = 1.f / (1.f + __expf(-z3));
        c = fg * c_use + ig * gg;
        float h = og * (1.f - 2.f / (1.f + __expf(2.f * c)));
        __syncthreads();
        hs[j] = h;
        ys[((size_t)(t * B_ + b)) * H_ + j] = h;
    }
    out[b * H_ + j] = c;
    out[B_ * H_ + b * H_ + j] = hs[j];
}

extern "C" void kernel_launch(void* const* d_in, const int* in_sizes, int n_in,
                              void* d_out, int out_size, void* d_ws, size_t ws_size,
                              hipStream_t stream) {
    const float* ins    = (const float*)d_in[0];
    const int*   resets = (const int*)d_in[1];
    const float* c0     = (const float*)d_in[2];
    const float* h0     = (const float*)d_in[3];
    const float* Wi     = (const float*)d_in[4];
    const float* Wh     = (const float*)d_in[5];
    const float* bv     = (const float*)d_in[6];
    float*       out    = (float*)d_out;

    const size_t MiB = 1ull << 20;
    const size_t o_chains = 0;              // sorted chain words (256KB)
    const size_t o_chainU = 1 * MiB;        // scratch (256KB)
    const size_t o_meta   = 2 * MiB;
    const size_t o_wit    = 64 * MiB;
    const size_t o_whg    = 66 * MiB;
    const size_t o_zg     = 68 * MiB;
    const size_t need     = o_zg + 256 * MiB;

    if (ws_size >= need) {
        char* ws = (char*)d_ws;
        _Float16* WiT    = (_Float16*)(ws + o_wit);
        _Float16* WhgT   = (_Float16*)(ws + o_whg);
        _Float16* Zg     = (_Float16*)(ws + o_zg);
        int*      chains = (int*)(ws + o_chains);
        int*      chainU = (int*)(ws + o_chainU);
        int*      meta   = (int*)(ws + o_meta);

        cvt_weights<<<8192, 256, 0, stream>>>(Wi, Wh, WiT, WhgT);
        gemm_xwi<<<dim3(T_ * B_ / 128, N4H / 128), 256, 0, stream>>>(ins, WiT, bv, Zg);
        chain_analysis<<<1, 256, 0, stream>>>(resets, chainU, chains, meta);
        lstm_chain<<<2048, 512, 0, stream>>>(Zg, WhgT, c0, h0, chains, meta, out);
    } else {
        lstm_fb<<<B_, H_, 0, stream>>>(ins, resets, c0, h0, Wi, Wh, bv, out);
    }
}